// Round 1
// baseline (1283.790 us; speedup 1.0000x reference)
//
#include <hip/hip_runtime.h>

// Problem constants (match reference)
constexpr int B  = 2;
constexpr int N  = 18432;
constexpr int C  = 1024;
constexpr int GR = 40;
constexpr int NV = GR * GR * GR;   // 64000
constexpr int INVALID_BIT = 1 << 30;

// ---------------------------------------------------------------------------
// Kernel 1: per-point voxel id, validity, count, per-batch max voxel id
// ---------------------------------------------------------------------------
__global__ void points_kernel(const float* __restrict__ xyz,
                              int* __restrict__ p2v,
                              int* __restrict__ cnt,
                              int* __restrict__ bmax) {
    int i = blockIdx.x * blockDim.x + threadIdx.x;   // over B*N points
    if (i >= B * N) return;
    int b = i / N;

    float x = xyz[3 * i + 0];
    float y = xyz[3 * i + 1];
    float z = xyz[3 * i + 2];

    bool valid = (x > -0.5f) && (x < 0.5f) &&
                 (y > -0.5f) && (y < 0.5f) &&
                 (z >  0.0f) && (z < 1.0f);

    // reference masks invalid xyz to 0 BEFORE voxelization
    float xm = valid ? x : 0.0f;
    float ym = valid ? y : 0.0f;
    float zm = valid ? z : 0.0f;

    // idx = floor((xyz - pc_min) / 0.025), clip to [0, 39]  (fp32, division as in ref)
    int ix = (int)floorf((xm + 0.5f) / 0.025f);
    int iy = (int)floorf((ym + 0.5f) / 0.025f);
    int iz = (int)floorf((zm - 0.0f) / 0.025f);
    ix = min(max(ix, 0), GR - 1);
    iy = min(max(iy, 0), GR - 1);
    iz = min(max(iz, 0), GR - 1);

    int v = ix + GR * iy + GR * GR * iz;

    // count ALL points (invalid ones contribute 0-features but +1 count, per ref)
    atomicAdd(&cnt[b * NV + v], 1);
    atomicMax(&bmax[b], v);

    p2v[i] = valid ? v : (v | INVALID_BIT);
}

// ---------------------------------------------------------------------------
// Kernel 2: scatter-add features of VALID points into d_out (pre-zeroed)
// one block (256 threads) per point, float4 per thread
// ---------------------------------------------------------------------------
__global__ void scatter_kernel(const float* __restrict__ feats,
                               const int* __restrict__ p2v,
                               float* __restrict__ out) {
    int i = blockIdx.x;                 // point index in [0, B*N)
    int v = p2v[i];
    if (v & INVALID_BIT) return;        // invalid: features masked to 0 in ref
    int b = i / N;

    const float4* src = (const float4*)(feats + (size_t)i * C);
    float*        dst = out + ((size_t)b * NV + (size_t)v) * C;

    float4 f = src[threadIdx.x];
    int c = threadIdx.x * 4;
    atomicAdd(&dst[c + 0], f.x);
    atomicAdd(&dst[c + 1], f.y);
    atomicAdd(&dst[c + 2], f.z);
    atomicAdd(&dst[c + 3], f.w);
}

// ---------------------------------------------------------------------------
// Kernel 3: divide voxels with cnt >= 2 by their count (cnt 0/1: already correct)
// one block (256 threads) per (b, voxel)
// ---------------------------------------------------------------------------
__global__ void norm_kernel(const int* __restrict__ cnt,
                            float* __restrict__ out) {
    int v = blockIdx.x;                 // [0, B*NV)
    int c = cnt[v];
    if (c < 2) return;
    float fc = (float)c;

    float4* p = (float4*)(out + (size_t)v * C);
    float4 f = p[threadIdx.x];
    f.x /= fc; f.y /= fc; f.z /= fc; f.w /= fc;
    p[threadIdx.x] = f;
}

// ---------------------------------------------------------------------------
// Kernel 4: batch_offset = cumsum(max voxel id per batch + 1), stored as float
// ---------------------------------------------------------------------------
__global__ void offs_kernel(const int* __restrict__ bmax,
                            float* __restrict__ out_offs) {
    if (threadIdx.x == 0 && blockIdx.x == 0) {
        int m0 = bmax[0];
        int m1 = bmax[1];
        out_offs[0] = (float)(m0 + 1);
        out_offs[1] = (float)(m0 + 1 + m1 + 1);
    }
}

// ---------------------------------------------------------------------------
extern "C" void kernel_launch(void* const* d_in, const int* in_sizes, int n_in,
                              void* d_out, int out_size, void* d_ws, size_t ws_size,
                              hipStream_t stream) {
    const float* feats = (const float*)d_in[0];   // (B, N, C) fp32
    const float* xyz   = (const float*)d_in[1];   // (B, N, 3) fp32
    float* out = (float*)d_out;                   // pooled (B,NV,C) then batch_offset (B,)

    // workspace layout (ints)
    int* p2v  = (int*)d_ws;        // B*N
    int* cnt  = p2v + B * N;       // B*NV
    int* bmax = cnt + B * NV;      // B

    // zero pooled output (poisoned 0xAA every timed call) + counters
    hipMemsetAsync(d_out, 0, (size_t)B * NV * C * sizeof(float), stream);
    hipMemsetAsync(cnt, 0, (size_t)(B * NV + B) * sizeof(int), stream);

    points_kernel<<<(B * N + 255) / 256, 256, 0, stream>>>(xyz, p2v, cnt, bmax);
    scatter_kernel<<<B * N, 256, 0, stream>>>(feats, p2v, out);
    norm_kernel<<<B * NV, 256, 0, stream>>>(cnt, out);
    offs_kernel<<<1, 64, 0, stream>>>(bmax, out + (size_t)B * NV * C);
}

// Round 2
// 647.464 us; speedup vs baseline: 1.9828x; 1.9828x over previous
//
#include <hip/hip_runtime.h>

// Problem constants (match reference)
constexpr int B  = 2;
constexpr int N  = 18432;          // divisible by 256 -> no tail lanes
constexpr int C  = 1024;
constexpr int GR = 40;
constexpr int NV = GR * GR * GR;   // 64000
constexpr int BNV = B * NV;        // 128000 = 500 * 256
constexpr int INVALID_BIT = 1 << 30;
constexpr int ZERO_VOX = 820;      // voxel id of masked-to-origin points: 20 + 40*20 + 0

// ---------------------------------------------------------------------------
// Kernel 1: per-point voxel id + validity; wave-aggregated count/max atomics
// ---------------------------------------------------------------------------
__global__ void points_kernel(const float* __restrict__ xyz,
                              int* __restrict__ p2v,
                              int* __restrict__ cntAll,
                              int* __restrict__ invCnt,
                              int* __restrict__ bmax) {
    int i = blockIdx.x * blockDim.x + threadIdx.x;   // [0, B*N), no tail
    int b = i / N;                                   // wave-uniform (N % 64 == 0)
    int lane = threadIdx.x & 63;

    float x = xyz[3 * i + 0];
    float y = xyz[3 * i + 1];
    float z = xyz[3 * i + 2];

    bool valid = (x > -0.5f) && (x < 0.5f) &&
                 (y > -0.5f) && (y < 0.5f) &&
                 (z >  0.0f) && (z < 1.0f);

    // reference masks invalid xyz to 0 BEFORE voxelization
    float xm = valid ? x : 0.0f;
    float ym = valid ? y : 0.0f;
    float zm = valid ? z : 0.0f;

    int ix = (int)floorf((xm + 0.5f) / 0.025f);
    int iy = (int)floorf((ym + 0.5f) / 0.025f);
    int iz = (int)floorf(zm / 0.025f);
    ix = min(max(ix, 0), GR - 1);
    iy = min(max(iy, 0), GR - 1);
    iz = min(max(iz, 0), GR - 1);
    int v = ix + GR * iy + GR * GR * iz;             // invalid -> ZERO_VOX (820)

    // per-batch max voxel id: wave shfl-reduce, one atomic per wave
    int m = v;
    #pragma unroll
    for (int o = 32; o >= 1; o >>= 1)
        m = max(m, __shfl_xor(m, o, 64));
    if (lane == 0) atomicMax(&bmax[b], m);

    // counts: valid lanes spread over 64000 voxels (low contention);
    // invalid lanes ALL hit voxel 820 -> aggregate per wave
    unsigned long long vb = __ballot(valid);
    int nInv = 64 - __popcll(vb);
    if (valid) {
        atomicAdd(&cntAll[b * NV + v], 1);
    }
    if (lane == 0 && nInv > 0) {
        atomicAdd(&cntAll[b * NV + ZERO_VOX], nInv);
        atomicAdd(&invCnt[b], nInv);
    }

    p2v[i] = valid ? v : (v | INVALID_BIT);
}

// ---------------------------------------------------------------------------
// Exclusive scan of valid-point counts (cntAll minus invalid at voxel 820)
// over BNV = 128000 = 500 blocks x 256
// ---------------------------------------------------------------------------
__global__ void scan1_kernel(const int* __restrict__ cntAll,
                             const int* __restrict__ invCnt,
                             int* __restrict__ offs,
                             int* __restrict__ bsum) {
    __shared__ int s[256];
    int idx = blockIdx.x * 256 + threadIdx.x;
    int b = idx / NV;
    int vv = idx - b * NV;
    int x = cntAll[idx] - ((vv == ZERO_VOX) ? invCnt[b] : 0);
    s[threadIdx.x] = x;
    __syncthreads();
    for (int o = 1; o < 256; o <<= 1) {
        int t = (threadIdx.x >= o) ? s[threadIdx.x - o] : 0;
        __syncthreads();
        s[threadIdx.x] += t;
        __syncthreads();
    }
    offs[idx] = s[threadIdx.x] - x;                  // exclusive
    if (threadIdx.x == 255) bsum[blockIdx.x] = s[255];
}

__global__ void scan2_kernel(const int* __restrict__ bsum,
                             int* __restrict__ bsumScan,
                             int* __restrict__ offs) {
    __shared__ int s[512];
    int x = (threadIdx.x < 500) ? bsum[threadIdx.x] : 0;
    s[threadIdx.x] = x;
    __syncthreads();
    for (int o = 1; o < 512; o <<= 1) {
        int t = (threadIdx.x >= o) ? s[threadIdx.x - o] : 0;
        __syncthreads();
        s[threadIdx.x] += t;
        __syncthreads();
    }
    if (threadIdx.x < 500) bsumScan[threadIdx.x] = s[threadIdx.x] - x;
    if (threadIdx.x == 511) offs[BNV] = s[511];      // grand total of valid points
}

__global__ void scan3_kernel(int* __restrict__ offs,
                             const int* __restrict__ bsumScan) {
    int idx = blockIdx.x * 256 + threadIdx.x;
    offs[idx] += bsumScan[blockIdx.x];
}

// ---------------------------------------------------------------------------
// Bin valid point indices into per-voxel contiguous lists
// ---------------------------------------------------------------------------
__global__ void fill_kernel(const int* __restrict__ p2v,
                            const int* __restrict__ offs,
                            int* __restrict__ fill,
                            int* __restrict__ plist) {
    int i = blockIdx.x * blockDim.x + threadIdx.x;   // [0, B*N)
    int pv = p2v[i];
    if (pv & INVALID_BIT) return;
    int g = (i / N) * NV + pv;
    int slot = atomicAdd(&fill[g], 1);
    plist[offs[g] + slot] = i;
}

// ---------------------------------------------------------------------------
// One block (256 threads, float4 each) per output voxel: sum -> mean -> single
// write. Empty voxels write zeros (this replaces the 524 MB memset).
// ---------------------------------------------------------------------------
__global__ void gather_kernel(const float* __restrict__ feats,
                              const int* __restrict__ plist,
                              const int* __restrict__ offs,
                              const int* __restrict__ cntAll,
                              float* __restrict__ out) {
    int g = blockIdx.x;                              // [0, B*NV)
    int start = offs[g];
    int end   = offs[g + 1];
    float inv = 1.0f / (float)max(cntAll[g], 1);     // denominator counts ALL points

    float4 acc = {0.0f, 0.0f, 0.0f, 0.0f};
    for (int j = start; j < end; ++j) {
        int p = plist[j];
        float4 f = ((const float4*)(feats + (size_t)p * C))[threadIdx.x];
        acc.x += f.x; acc.y += f.y; acc.z += f.z; acc.w += f.w;
    }
    float4 o = {acc.x * inv, acc.y * inv, acc.z * inv, acc.w * inv};
    ((float4*)(out + (size_t)g * C))[threadIdx.x] = o;
}

// ---------------------------------------------------------------------------
__global__ void offs_out_kernel(const int* __restrict__ bmax,
                                float* __restrict__ out_offs) {
    if (threadIdx.x == 0 && blockIdx.x == 0) {
        int m0 = bmax[0];
        int m1 = bmax[1];
        out_offs[0] = (float)(m0 + 1);
        out_offs[1] = (float)(m0 + 1 + m1 + 1);
    }
}

// ---------------------------------------------------------------------------
extern "C" void kernel_launch(void* const* d_in, const int* in_sizes, int n_in,
                              void* d_out, int out_size, void* d_ws, size_t ws_size,
                              hipStream_t stream) {
    const float* feats = (const float*)d_in[0];   // (B, N, C) fp32
    const float* xyz   = (const float*)d_in[1];   // (B, N, 3) fp32
    float* out = (float*)d_out;                   // pooled (B,NV,C) ++ batch_offset (B,)

    // workspace layout (int32), zero-region first so one memset covers it
    int* w        = (int*)d_ws;
    int* cntAll   = w;                   // BNV
    int* fill     = cntAll + BNV;        // BNV
    int* invCnt   = fill + BNV;          // B
    int* bmax     = invCnt + B;          // B
    int* offs     = bmax + B;            // BNV + 1
    int* bsum     = offs + BNV + 1;      // 500
    int* bsumScan = bsum + 500;          // 500
    int* p2v      = bsumScan + 500;      // B*N
    int* plist    = p2v + B * N;         // B*N

    hipMemsetAsync(cntAll, 0, (size_t)(2 * BNV + 2 * B) * sizeof(int), stream);

    points_kernel<<<(B * N) / 256, 256, 0, stream>>>(xyz, p2v, cntAll, invCnt, bmax);
    scan1_kernel<<<BNV / 256, 256, 0, stream>>>(cntAll, invCnt, offs, bsum);
    scan2_kernel<<<1, 512, 0, stream>>>(bsum, bsumScan, offs);
    scan3_kernel<<<BNV / 256, 256, 0, stream>>>(offs, bsumScan);
    fill_kernel<<<(B * N) / 256, 256, 0, stream>>>(p2v, offs, fill, plist);
    gather_kernel<<<BNV, 256, 0, stream>>>(feats, plist, offs, cntAll, out);
    offs_out_kernel<<<1, 64, 0, stream>>>(bmax, out + (size_t)B * NV * C);
}

// Round 3
// 607.438 us; speedup vs baseline: 2.1134x; 1.0659x over previous
//
#include <hip/hip_runtime.h>

// Problem constants (match reference)
constexpr int B  = 2;
constexpr int N  = 18432;          // divisible by 256 -> no tail lanes
constexpr int C  = 1024;
constexpr int GR = 40;
constexpr int NV = GR * GR * GR;   // 64000
constexpr int BNV = B * NV;        // 128000
constexpr int ZERO_VOX = 820;      // voxel of masked-to-origin points: 20 + 40*20

typedef float v4f __attribute__((ext_vector_type(4)));

// ---------------------------------------------------------------------------
// Kernel 1: per-point voxel id + validity; wave-aggregated hot atomics;
// valid points pushed onto a per-voxel linked list (head holds i+1, 0=empty).
// ---------------------------------------------------------------------------
__global__ void points_kernel(const float* __restrict__ xyz,
                              int* __restrict__ cntAll,
                              int* __restrict__ head,
                              int* __restrict__ nxt,
                              int* __restrict__ bmax) {
    int i = blockIdx.x * blockDim.x + threadIdx.x;   // [0, B*N), no tail
    int b = i / N;                                   // wave-uniform (N % 64 == 0)
    int lane = threadIdx.x & 63;

    float x = xyz[3 * i + 0];
    float y = xyz[3 * i + 1];
    float z = xyz[3 * i + 2];

    bool valid = (x > -0.5f) && (x < 0.5f) &&
                 (y > -0.5f) && (y < 0.5f) &&
                 (z >  0.0f) && (z < 1.0f);

    // reference masks invalid xyz to 0 BEFORE voxelization
    float xm = valid ? x : 0.0f;
    float ym = valid ? y : 0.0f;
    float zm = valid ? z : 0.0f;

    int ix = min(max((int)floorf((xm + 0.5f) / 0.025f), 0), GR - 1);
    int iy = min(max((int)floorf((ym + 0.5f) / 0.025f), 0), GR - 1);
    int iz = min(max((int)floorf(zm / 0.025f), 0), GR - 1);
    int v = ix + GR * iy + GR * GR * iz;             // invalid -> ZERO_VOX

    // per-batch max voxel id: shfl-reduce, one atomic per wave
    int m = v;
    #pragma unroll
    for (int o = 32; o >= 1; o >>= 1)
        m = max(m, __shfl_xor(m, o, 64));
    if (lane == 0) atomicMax(&bmax[b], m);

    // denominator counts ALL points; invalid lanes all hit ZERO_VOX -> one
    // aggregated atomic per wave instead of ~27 serialized same-address adds
    unsigned long long vb = __ballot(valid);
    int nInv = 64 - __popcll(vb);
    if (lane == 0 && nInv > 0) atomicAdd(&cntAll[b * NV + ZERO_VOX], nInv);

    if (valid) {
        int g = b * NV + v;
        atomicAdd(&cntAll[g], 1);
        nxt[i] = atomicExch(&head[g], i + 1);        // push onto voxel list
    }
}

// ---------------------------------------------------------------------------
// Kernel 2: one block (256 threads, float4 each) per output voxel. Walk the
// (short) point list, sum, multiply by 1/cnt, single nontemporal write.
// Empty voxels write zeros — this replaces any output memset.
// ---------------------------------------------------------------------------
__global__ void gather_kernel(const float* __restrict__ feats,
                              const int* __restrict__ head,
                              const int* __restrict__ nxt,
                              const int* __restrict__ cntAll,
                              float* __restrict__ out) {
    int g = blockIdx.x;                              // [0, B*NV)
    int p = head[g];
    float inv = 1.0f / (float)max(cntAll[g], 1);

    v4f acc = {0.0f, 0.0f, 0.0f, 0.0f};
    while (p) {
        int pn = nxt[p - 1];                         // prefetch next link
        const v4f* src = (const v4f*)(feats + (size_t)(p - 1) * C);
        v4f f = src[threadIdx.x];
        acc += f;
        p = pn;
    }
    acc *= inv;
    v4f* dst = (v4f*)(out + (size_t)g * C);
    __builtin_nontemporal_store(acc, dst + threadIdx.x);
}

// ---------------------------------------------------------------------------
// Kernel 3: batch_offset = cumsum(max voxel id per batch + 1), as float
// ---------------------------------------------------------------------------
__global__ void offs_out_kernel(const int* __restrict__ bmax,
                                float* __restrict__ out_offs) {
    if (threadIdx.x == 0 && blockIdx.x == 0) {
        int m0 = bmax[0];
        int m1 = bmax[1];
        out_offs[0] = (float)(m0 + 1);
        out_offs[1] = (float)(m0 + 1 + m1 + 1);
    }
}

// ---------------------------------------------------------------------------
extern "C" void kernel_launch(void* const* d_in, const int* in_sizes, int n_in,
                              void* d_out, int out_size, void* d_ws, size_t ws_size,
                              hipStream_t stream) {
    const float* feats = (const float*)d_in[0];   // (B, N, C) fp32
    const float* xyz   = (const float*)d_in[1];   // (B, N, 3) fp32
    float* out = (float*)d_out;                   // pooled (B,NV,C) ++ batch_offset (B,)

    // workspace layout (int32): zeroed region first, one memset covers it
    int* w      = (int*)d_ws;
    int* cntAll = w;                 // BNV   (zeroed)
    int* head   = cntAll + BNV;      // BNV   (zeroed; 0 = empty list)
    int* bmax   = head + BNV;        // B     (zeroed)
    int* nxt    = bmax + B;          // B*N   (no init needed)

    hipMemsetAsync(cntAll, 0, (size_t)(2 * BNV + B) * sizeof(int), stream);

    points_kernel<<<(B * N) / 256, 256, 0, stream>>>(xyz, cntAll, head, nxt, bmax);
    gather_kernel<<<BNV, 256, 0, stream>>>(feats, head, nxt, cntAll, out);
    offs_out_kernel<<<1, 64, 0, stream>>>(bmax, out + (size_t)B * NV * C);
}